// Round 8
// baseline (282.219 us; speedup 1.0000x reference)
//
#include <hip/hip_runtime.h>

#define BETA   0.1f
#define MARGIN 0.1f
#define EPSF   1e-6f
#define KNEG   4

__device__ __forceinline__ float gsum16(float v) {
    #pragma unroll
    for (int off = 8; off >= 1; off >>= 1) v += __shfl_xor(v, off, 64);
    return v;
}
__device__ __forceinline__ float gmax16(float v) {
    #pragma unroll
    for (int off = 8; off >= 1; off >>= 1) v = fmaxf(v, __shfl_xor(v, off, 64));
    return v;
}
__device__ __forceinline__ float wave_sum(float v) {
    #pragma unroll
    for (int off = 32; off >= 1; off >>= 1) v += __shfl_xor(v, off, 64);
    return v;
}
__device__ __forceinline__ float dot4(float4 a, float4 b) {
    return a.x*b.x + a.y*b.y + a.z*b.z + a.w*b.w;
}

// ---- pass 1: int4 table (128 B/row) + side table {norm2, aperture, scale} ----
__global__ __launch_bounds__(256) void cvt_i4(
    const float* __restrict__ in, uint2* __restrict__ tab,
    float4* __restrict__ side, int C)
{
    const int sl  = threadIdx.x & 15;
    const int row = (blockIdx.x * 256 + threadIdx.x) >> 4;
    if (row >= C) return;
    const float4* src = (const float4*)(in + (size_t)row * 256);
    float4 v0 = src[4*sl+0], v1 = src[4*sl+1], v2 = src[4*sl+2], v3 = src[4*sl+3];
    float f[16] = { v0.x, v0.y, v0.z, v0.w,  v1.x, v1.y, v1.z, v1.w,
                    v2.x, v2.y, v2.z, v2.w,  v3.x, v3.y, v3.z, v3.w };
    float am = 0.f;
    #pragma unroll
    for (int d = 0; d < 16; ++d) am = fmaxf(am, fabsf(f[d]));
    am = gmax16(am);
    const float inv = (am > 0.f) ? (7.5f / am) : 0.f;
    unsigned u0 = 0, u1 = 0;
    #pragma unroll
    for (int n = 0; n < 8; ++n) {
        int c = (int)rintf(f[n] * inv);
        c = (c < -8) ? -8 : ((c > 7) ? 7 : c);
        u0 |= (unsigned)(c + 8) << (4 * n);
    }
    #pragma unroll
    for (int n = 0; n < 8; ++n) {
        int c = (int)rintf(f[8 + n] * inv);
        c = (c < -8) ? -8 : ((c > 7) ? 7 : c);
        u1 |= (unsigned)(c + 8) << (4 * n);
    }
    tab[(size_t)row * 16 + sl] = make_uint2(u0, u1);
    float ss = gsum16(dot4(v0,v0) + dot4(v1,v1) + dot4(v2,v2) + dot4(v3,v3));
    if (sl == 0) {
        float np = sqrtf(ss);
        float ap = asinf(fminf(fmaxf(BETA / (np + EPSF), 0.f), 1.f - EPSF));
        side[row] = make_float4(ss, ap, am * (1.f / 7.5f), 0.f);
    }
}

__device__ __forceinline__ float codes_dot(uint2 cu, const float* pf) {
    float acc = 0.f;
    #pragma unroll
    for (int n = 0; n < 8; ++n)
        acc = fmaf((float)((cu.x >> (4*n)) & 0xF), pf[n], acc);
    #pragma unroll
    for (int n = 0; n < 8; ++n)
        acc = fmaf((float)((cu.y >> (4*n)) & 0xF), pf[8 + n], acc);
    return acc;
}

// ---- pass 2: gather + energy + fused finalize. NO dynamic array indexing:
// indices are named scalars, j-loop macro-unrolled (R7's idx[sl-1] went to
// scratch -> serialized all row loads behind scratch reads -> 125us).
__global__ __launch_bounds__(256) void cone_main_i4(
    const uint2*  __restrict__ tab,
    const float4* __restrict__ side,
    const int*    __restrict__ pairs,
    const int*    __restrict__ negc,
    float*        __restrict__ part,
    unsigned*     __restrict__ counter,
    float*        __restrict__ out,
    int P, int nblocks)
{
    const int lane = threadIdx.x & 63;
    const int wid  = threadIdx.x >> 6;
    const int sub  = lane >> 4;
    const int sl   = lane & 15;
    const int pair = (blockIdx.x * 4 + wid) * 4 + sub;

    float pos_e = 0.f, neg_e = 0.f;
    if (pair < P) {
        const int pi = pairs[2 * pair];
        const int i0 = pairs[2 * pair + 1];
        const int i1 = negc[4 * pair + 0];
        const int i2 = negc[4 * pair + 1];
        const int i3 = negc[4 * pair + 2];
        const int i4 = negc[4 * pair + 3];

        // 6 row loads (128 B each) issued up-front, all in registers.
        uint2 pu  = tab[(size_t)pi * 16 + sl];
        uint2 cu0 = tab[(size_t)i0 * 16 + sl];
        uint2 cu1 = tab[(size_t)i1 * 16 + sl];
        uint2 cu2 = tab[(size_t)i2 * 16 + sl];
        uint2 cu3 = tab[(size_t)i3 * 16 + sl];
        uint2 cu4 = tab[(size_t)i4 * 16 + sl];

        // Side gather: lane sl in 1..5 loads side[i_{sl-1}], others side[pi].
        int tidx = pi;
        tidx = (sl == 1) ? i0 : tidx;
        tidx = (sl == 2) ? i1 : tidx;
        tidx = (sl == 3) ? i2 : tidx;
        tidx = (sl == 4) ? i3 : tidx;
        tidx = (sl == 5) ? i4 : tidx;
        float4 sd = side[tidx];

        const int base = sub * 16;
        const float p2 = __shfl(sd.x, base + 0, 64);
        const float ap = __shfl(sd.y, base + 0, 64);
        const float sp = __shfl(sd.z, base + 0, 64);
        const float np = sqrtf(p2);

        float pf[16];
        #pragma unroll
        for (int n = 0; n < 8; ++n) pf[n]     = (float)((pu.x >> (4*n)) & 0xF) - 8.f;
        #pragma unroll
        for (int n = 0; n < 8; ++n) pf[8 + n] = (float)((pu.y >> (4*n)) & 0xF) - 8.f;
        float s = 0.f;
        #pragma unroll
        for (int d = 0; d < 16; ++d) s += pf[d];
        const float SP = gsum16(s);          // sum of centered p codes (exact)

#define CONE_STEP(J, CU)                                                      \
        {                                                                     \
            const float draw = gsum16(codes_dot(CU, pf)) - 8.f * SP;          \
            const float c2 = __shfl(sd.x, base + 1 + J, 64);                  \
            const float sc = __shfl(sd.z, base + 1 + J, 64);                  \
            const float dot = draw * sp * sc;                                 \
            const float num = 2.f * (dot - p2);                               \
            const float d2  = fmaxf(c2 + p2 - 2.f * dot, 0.f);                \
            const float den = 2.f * np * sqrtf(d2) + EPSF;                    \
            const float ca  = fminf(fmaxf(num / den, -1.f + EPSF), 1.f - EPSF);\
            const float e   = fmaxf(acosf(ca) - ap, 0.f);                     \
            if (J == 0) pos_e = e;                                            \
            else        neg_e += fmaxf(MARGIN - e, 0.f);                      \
        }
        CONE_STEP(0, cu0)
        CONE_STEP(1, cu1)
        CONE_STEP(2, cu2)
        CONE_STEP(3, cu3)
        CONE_STEP(4, cu4)
#undef CONE_STEP
    }

    __shared__ float spos[16], sneg[16];
    __shared__ int   isLast;
    if (sl == 0) { spos[wid * 4 + sub] = pos_e; sneg[wid * 4 + sub] = neg_e; }
    __syncthreads();
    if (threadIdx.x == 0) {
        float ps = 0.f, ns = 0.f;
        #pragma unroll
        for (int i = 0; i < 16; ++i) { ps += spos[i]; ns += sneg[i]; }
        part[2 * blockIdx.x]     = ps;
        part[2 * blockIdx.x + 1] = ns;
        __threadfence();
        unsigned t = atomicAdd(counter, 1u);
        isLast = (t == (unsigned)(nblocks - 1));
    }
    __syncthreads();
    if (isLast) {
        float ps = 0.f, ns = 0.f;
        for (int i = threadIdx.x; i < nblocks; i += 256) {
            ps += part[2 * i];
            ns += part[2 * i + 1];
        }
        ps = wave_sum(ps);
        ns = wave_sum(ns);
        if (sl == 0 && sub == 0) { spos[wid] = ps; sneg[wid] = ns; }
        __syncthreads();
        if (threadIdx.x == 0) {
            float tp = spos[0] + spos[1] + spos[2] + spos[3];
            float tn = sneg[0] + sneg[1] + sneg[2] + sneg[3];
            float fP = (float)P;
            out[0] = (tp / fP + tn / (fP * (float)KNEG)) * 0.5f;
        }
    }
}

// ---- fp32 fallback (R2 kernel) if ws can't hold the tables ----
__global__ __launch_bounds__(256) void cone_main_f32(
    const float* __restrict__ proto,
    const int*   __restrict__ pairs,
    const int*   __restrict__ negc,
    float*       __restrict__ part,
    int P)
{
    const int lane = threadIdx.x & 63;
    const int wid  = threadIdx.x >> 6;
    const int sub  = lane >> 4;
    const int sl   = lane & 15;
    const int pair = (blockIdx.x * 4 + wid) * 4 + sub;

    float pos_e = 0.f, neg_e = 0.f;
    if (pair < P) {
        const int pi = pairs[2 * pair];
        const int i0 = pairs[2 * pair + 1];
        const int i1 = negc[4 * pair + 0];
        const int i2 = negc[4 * pair + 1];
        const int i3 = negc[4 * pair + 2];
        const int i4 = negc[4 * pair + 3];

        const float4* prow = (const float4*)(proto + (size_t)pi * 256);
        float4 pv[4];
        #pragma unroll
        for (int r = 0; r < 4; ++r) pv[r] = prow[sl + 16 * r];

        float pp = 0.f;
        #pragma unroll
        for (int r = 0; r < 4; ++r) pp += dot4(pv[r], pv[r]);
        float p2     = gsum16(pp);
        float norm_p = sqrtf(p2);
        float apert  = asinf(fminf(fmaxf(BETA / (norm_p + EPSF), 0.f), 1.f - EPSF));

#define CONE_F32_STEP(J, IDX)                                                 \
        {                                                                     \
            const float4* crow = (const float4*)(proto + (size_t)(IDX) * 256);\
            float cc = 0.f, dd = 0.f;                                         \
            _Pragma("unroll")                                                 \
            for (int r = 0; r < 4; ++r) {                                     \
                float4 c = crow[sl + 16 * r], p = pv[r];                      \
                cc += dot4(c, c);                                             \
                float dx = c.x-p.x, dy = c.y-p.y, dz = c.z-p.z, dw = c.w-p.w; \
                dd += dx*dx + dy*dy + dz*dz + dw*dw;                          \
            }                                                                 \
            float c2 = gsum16(cc);                                            \
            float d2 = gsum16(dd);                                            \
            float num    = c2 - p2 - d2;                                      \
            float den    = 2.f * norm_p * sqrtf(d2) + EPSF;                   \
            float cosang = fminf(fmaxf(num / den, -1.f + EPSF), 1.f - EPSF);  \
            float e      = fmaxf(acosf(cosang) - apert, 0.f);                 \
            if (J == 0) pos_e = e;                                            \
            else        neg_e += fmaxf(MARGIN - e, 0.f);                      \
        }
        CONE_F32_STEP(0, i0)
        CONE_F32_STEP(1, i1)
        CONE_F32_STEP(2, i2)
        CONE_F32_STEP(3, i3)
        CONE_F32_STEP(4, i4)
#undef CONE_F32_STEP
    }

    __shared__ float sp[16], sn[16];
    if (sl == 0) { sp[wid * 4 + sub] = pos_e; sn[wid * 4 + sub] = neg_e; }
    __syncthreads();
    if (threadIdx.x == 0) {
        float ps = 0.f, ns = 0.f;
        #pragma unroll
        for (int i = 0; i < 16; ++i) { ps += sp[i]; ns += sn[i]; }
        part[2 * blockIdx.x]     = ps;
        part[2 * blockIdx.x + 1] = ns;
    }
}

__global__ __launch_bounds__(1024) void cone_final(
    const float* __restrict__ part, float* __restrict__ out, int nblocks, int P)
{
    float ps = 0.f, ns = 0.f;
    for (int i = threadIdx.x; i < nblocks; i += 1024) {
        ps += part[2 * i];
        ns += part[2 * i + 1];
    }
    ps = wave_sum(ps);
    ns = wave_sum(ns);
    const int lane = threadIdx.x & 63, wid = threadIdx.x >> 6;
    __shared__ float sp[16], sn[16];
    if (lane == 0) { sp[wid] = ps; sn[wid] = ns; }
    __syncthreads();
    if (threadIdx.x == 0) {
        float tp = 0.f, tn = 0.f;
        #pragma unroll
        for (int i = 0; i < 16; ++i) { tp += sp[i]; tn += sn[i]; }
        float fP = (float)P;
        out[0] = (tp / fP + tn / (fP * (float)KNEG)) * 0.5f;
    }
}

extern "C" void kernel_launch(void* const* d_in, const int* in_sizes, int n_in,
                              void* d_out, int out_size, void* d_ws, size_t ws_size,
                              hipStream_t stream) {
    const float* proto = (const float*)d_in[0];
    const int*   pairs = (const int*)d_in[1];
    const int*   negc  = (const int*)d_in[2];
    const int P = in_sizes[1] / 2;
    const int C = in_sizes[0] / 256;
    const int nblocks = (P + 15) / 16;

    const size_t tab_bytes  = (size_t)C * 128;
    const size_t side_bytes = (size_t)C * 16;
    const size_t part_bytes = (size_t)nblocks * 2 * sizeof(float);
    const size_t need = tab_bytes + side_bytes + part_bytes + 256;

    if (ws_size >= need) {
        char* base = (char*)d_ws;
        uint2*    tab     = (uint2*)base;
        float4*   side    = (float4*)(base + tab_bytes);
        float*    part    = (float*)(base + tab_bytes + side_bytes);
        unsigned* counter = (unsigned*)(base + tab_bytes + side_bytes + part_bytes);

        hipMemsetAsync(counter, 0, sizeof(unsigned), stream);
        cvt_i4<<<(C + 15) / 16, 256, 0, stream>>>(proto, tab, side, C);
        cone_main_i4<<<nblocks, 256, 0, stream>>>(tab, side, pairs, negc, part,
                                                  counter, (float*)d_out, P, nblocks);
    } else {
        float* part = (float*)d_ws;
        cone_main_f32<<<nblocks, 256, 0, stream>>>(proto, pairs, negc, part, P);
        cone_final<<<1, 1024, 0, stream>>>(part, (float*)d_out, nblocks, P);
    }
}

// Round 9
// 172.344 us; speedup vs baseline: 1.6375x; 1.6375x over previous
//
#include <hip/hip_runtime.h>

#define BETA   0.1f
#define MARGIN 0.1f
#define EPSF   1e-6f
#define KNEG   4

__device__ __forceinline__ float gsum16(float v) {
    #pragma unroll
    for (int off = 8; off >= 1; off >>= 1) v += __shfl_xor(v, off, 64);
    return v;
}
__device__ __forceinline__ float gmax16(float v) {
    #pragma unroll
    for (int off = 8; off >= 1; off >>= 1) v = fmaxf(v, __shfl_xor(v, off, 64));
    return v;
}
__device__ __forceinline__ float wave_sum(float v) {
    #pragma unroll
    for (int off = 32; off >= 1; off >>= 1) v += __shfl_xor(v, off, 64);
    return v;
}
__device__ __forceinline__ float dot4(float4 a, float4 b) {
    return a.x*b.x + a.y*b.y + a.z*b.z + a.w*b.w;
}

// ---- pass 1: int4 table (128 B/row) + side table {norm2, aperture, scale} ----
__global__ __launch_bounds__(256) void cvt_i4(
    const float* __restrict__ in, uint2* __restrict__ tab,
    float4* __restrict__ side, int C)
{
    const int sl  = threadIdx.x & 15;
    const int row = (blockIdx.x * 256 + threadIdx.x) >> 4;
    if (row >= C) return;
    const float4* src = (const float4*)(in + (size_t)row * 256);
    float4 v0 = src[4*sl+0], v1 = src[4*sl+1], v2 = src[4*sl+2], v3 = src[4*sl+3];
    float f[16] = { v0.x, v0.y, v0.z, v0.w,  v1.x, v1.y, v1.z, v1.w,
                    v2.x, v2.y, v2.z, v2.w,  v3.x, v3.y, v3.z, v3.w };
    float am = 0.f;
    #pragma unroll
    for (int d = 0; d < 16; ++d) am = fmaxf(am, fabsf(f[d]));
    am = gmax16(am);
    const float inv = (am > 0.f) ? (7.5f / am) : 0.f;
    unsigned u0 = 0, u1 = 0;
    #pragma unroll
    for (int n = 0; n < 8; ++n) {
        int c = (int)rintf(f[n] * inv);
        c = (c < -8) ? -8 : ((c > 7) ? 7 : c);
        u0 |= (unsigned)(c + 8) << (4 * n);
    }
    #pragma unroll
    for (int n = 0; n < 8; ++n) {
        int c = (int)rintf(f[8 + n] * inv);
        c = (c < -8) ? -8 : ((c > 7) ? 7 : c);
        u1 |= (unsigned)(c + 8) << (4 * n);
    }
    tab[(size_t)row * 16 + sl] = make_uint2(u0, u1);
    float ss = gsum16(dot4(v0,v0) + dot4(v1,v1) + dot4(v2,v2) + dot4(v3,v3));
    if (sl == 0) {
        float np = sqrtf(ss);
        float ap = asinf(fminf(fmaxf(BETA / (np + EPSF), 0.f), 1.f - EPSF));
        side[row] = make_float4(ss, ap, am * (1.f / 7.5f), 0.f);
    }
}

__device__ __forceinline__ float codes_dot(uint2 cu, const float* pf) {
    float acc = 0.f;
    #pragma unroll
    for (int n = 0; n < 8; ++n)
        acc = fmaf((float)((cu.x >> (4*n)) & 0xF), pf[n], acc);
    #pragma unroll
    for (int n = 0; n < 8; ++n)
        acc = fmaf((float)((cu.y >> (4*n)) & 0xF), pf[8 + n], acc);
    return acc;
}

// ---- pass 2: gather + energy. NO per-block __threadfence/atomic (R7/R8's
// fused finalize emitted per-block L2 wb/inv -> table evicted -> 128us).
// Partials written per block; separate tiny cone_final reduces them.
__global__ __launch_bounds__(256) void cone_main_i4(
    const uint2*  __restrict__ tab,
    const float4* __restrict__ side,
    const int*    __restrict__ pairs,
    const int*    __restrict__ negc,
    float*        __restrict__ part,
    int P)
{
    const int lane = threadIdx.x & 63;
    const int wid  = threadIdx.x >> 6;
    const int sub  = lane >> 4;
    const int sl   = lane & 15;
    const int pair = (blockIdx.x * 4 + wid) * 4 + sub;

    float pos_e = 0.f, neg_e = 0.f;
    if (pair < P) {
        const int pi = pairs[2 * pair];
        const int i0 = pairs[2 * pair + 1];
        const int i1 = negc[4 * pair + 0];
        const int i2 = negc[4 * pair + 1];
        const int i3 = negc[4 * pair + 2];
        const int i4 = negc[4 * pair + 3];

        // Issue ALL loads (6 rows + side) before any unpack/compute.
        uint2 pu  = tab[(size_t)pi * 16 + sl];
        uint2 cu0 = tab[(size_t)i0 * 16 + sl];
        uint2 cu1 = tab[(size_t)i1 * 16 + sl];
        uint2 cu2 = tab[(size_t)i2 * 16 + sl];
        uint2 cu3 = tab[(size_t)i3 * 16 + sl];
        uint2 cu4 = tab[(size_t)i4 * 16 + sl];

        int tidx = pi;
        tidx = (sl == 1) ? i0 : tidx;
        tidx = (sl == 2) ? i1 : tidx;
        tidx = (sl == 3) ? i2 : tidx;
        tidx = (sl == 4) ? i3 : tidx;
        tidx = (sl == 5) ? i4 : tidx;
        float4 sd = side[tidx];

        const int base = sub * 16;
        const float p2 = __shfl(sd.x, base + 0, 64);
        const float ap = __shfl(sd.y, base + 0, 64);
        const float sp = __shfl(sd.z, base + 0, 64);
        const float np = sqrtf(p2);

        float pf[16];
        #pragma unroll
        for (int n = 0; n < 8; ++n) pf[n]     = (float)((pu.x >> (4*n)) & 0xF) - 8.f;
        #pragma unroll
        for (int n = 0; n < 8; ++n) pf[8 + n] = (float)((pu.y >> (4*n)) & 0xF) - 8.f;
        float s = 0.f;
        #pragma unroll
        for (int d = 0; d < 16; ++d) s += pf[d];
        const float SP = gsum16(s);          // sum of centered p codes (exact)

#define CONE_STEP(J, CU)                                                      \
        {                                                                     \
            const float draw = gsum16(codes_dot(CU, pf)) - 8.f * SP;          \
            const float c2 = __shfl(sd.x, base + 1 + J, 64);                  \
            const float sc = __shfl(sd.z, base + 1 + J, 64);                  \
            const float dot = draw * sp * sc;                                 \
            const float num = 2.f * (dot - p2);                               \
            const float d2  = fmaxf(c2 + p2 - 2.f * dot, 0.f);                \
            const float den = 2.f * np * sqrtf(d2) + EPSF;                    \
            const float ca  = fminf(fmaxf(num / den, -1.f + EPSF), 1.f - EPSF);\
            const float e   = fmaxf(acosf(ca) - ap, 0.f);                     \
            if (J == 0) pos_e = e;                                            \
            else        neg_e += fmaxf(MARGIN - e, 0.f);                      \
        }
        CONE_STEP(0, cu0)
        CONE_STEP(1, cu1)
        CONE_STEP(2, cu2)
        CONE_STEP(3, cu3)
        CONE_STEP(4, cu4)
#undef CONE_STEP
    }

    __shared__ float spos[16], sneg[16];
    if (sl == 0) { spos[wid * 4 + sub] = pos_e; sneg[wid * 4 + sub] = neg_e; }
    __syncthreads();
    if (threadIdx.x == 0) {
        float ps = 0.f, ns = 0.f;
        #pragma unroll
        for (int i = 0; i < 16; ++i) { ps += spos[i]; ns += sneg[i]; }
        part[2 * blockIdx.x]     = ps;
        part[2 * blockIdx.x + 1] = ns;
    }
}

// ---- fp32 fallback (R2 kernel) if ws can't hold the tables ----
__global__ __launch_bounds__(256) void cone_main_f32(
    const float* __restrict__ proto,
    const int*   __restrict__ pairs,
    const int*   __restrict__ negc,
    float*       __restrict__ part,
    int P)
{
    const int lane = threadIdx.x & 63;
    const int wid  = threadIdx.x >> 6;
    const int sub  = lane >> 4;
    const int sl   = lane & 15;
    const int pair = (blockIdx.x * 4 + wid) * 4 + sub;

    float pos_e = 0.f, neg_e = 0.f;
    if (pair < P) {
        const int pi = pairs[2 * pair];
        const int i0 = pairs[2 * pair + 1];
        const int i1 = negc[4 * pair + 0];
        const int i2 = negc[4 * pair + 1];
        const int i3 = negc[4 * pair + 2];
        const int i4 = negc[4 * pair + 3];

        const float4* prow = (const float4*)(proto + (size_t)pi * 256);
        float4 pv[4];
        #pragma unroll
        for (int r = 0; r < 4; ++r) pv[r] = prow[sl + 16 * r];

        float pp = 0.f;
        #pragma unroll
        for (int r = 0; r < 4; ++r) pp += dot4(pv[r], pv[r]);
        float p2     = gsum16(pp);
        float norm_p = sqrtf(p2);
        float apert  = asinf(fminf(fmaxf(BETA / (norm_p + EPSF), 0.f), 1.f - EPSF));

#define CONE_F32_STEP(J, IDX)                                                 \
        {                                                                     \
            const float4* crow = (const float4*)(proto + (size_t)(IDX) * 256);\
            float cc = 0.f, dd = 0.f;                                         \
            _Pragma("unroll")                                                 \
            for (int r = 0; r < 4; ++r) {                                     \
                float4 c = crow[sl + 16 * r], p = pv[r];                      \
                cc += dot4(c, c);                                             \
                float dx = c.x-p.x, dy = c.y-p.y, dz = c.z-p.z, dw = c.w-p.w; \
                dd += dx*dx + dy*dy + dz*dz + dw*dw;                          \
            }                                                                 \
            float c2 = gsum16(cc);                                            \
            float d2 = gsum16(dd);                                            \
            float num    = c2 - p2 - d2;                                      \
            float den    = 2.f * norm_p * sqrtf(d2) + EPSF;                   \
            float cosang = fminf(fmaxf(num / den, -1.f + EPSF), 1.f - EPSF);  \
            float e      = fmaxf(acosf(cosang) - apert, 0.f);                 \
            if (J == 0) pos_e = e;                                            \
            else        neg_e += fmaxf(MARGIN - e, 0.f);                      \
        }
        CONE_F32_STEP(0, i0)
        CONE_F32_STEP(1, i1)
        CONE_F32_STEP(2, i2)
        CONE_F32_STEP(3, i3)
        CONE_F32_STEP(4, i4)
#undef CONE_F32_STEP
    }

    __shared__ float sp[16], sn[16];
    if (sl == 0) { sp[wid * 4 + sub] = pos_e; sn[wid * 4 + sub] = neg_e; }
    __syncthreads();
    if (threadIdx.x == 0) {
        float ps = 0.f, ns = 0.f;
        #pragma unroll
        for (int i = 0; i < 16; ++i) { ps += sp[i]; ns += sn[i]; }
        part[2 * blockIdx.x]     = ps;
        part[2 * blockIdx.x + 1] = ns;
    }
}

__global__ __launch_bounds__(1024) void cone_final(
    const float* __restrict__ part, float* __restrict__ out, int nblocks, int P)
{
    float ps = 0.f, ns = 0.f;
    for (int i = threadIdx.x; i < nblocks; i += 1024) {
        ps += part[2 * i];
        ns += part[2 * i + 1];
    }
    ps = wave_sum(ps);
    ns = wave_sum(ns);
    const int lane = threadIdx.x & 63, wid = threadIdx.x >> 6;
    __shared__ float sp[16], sn[16];
    if (lane == 0) { sp[wid] = ps; sn[wid] = ns; }
    __syncthreads();
    if (threadIdx.x == 0) {
        float tp = 0.f, tn = 0.f;
        #pragma unroll
        for (int i = 0; i < 16; ++i) { tp += sp[i]; tn += sn[i]; }
        float fP = (float)P;
        out[0] = (tp / fP + tn / (fP * (float)KNEG)) * 0.5f;
    }
}

extern "C" void kernel_launch(void* const* d_in, const int* in_sizes, int n_in,
                              void* d_out, int out_size, void* d_ws, size_t ws_size,
                              hipStream_t stream) {
    const float* proto = (const float*)d_in[0];
    const int*   pairs = (const int*)d_in[1];
    const int*   negc  = (const int*)d_in[2];
    const int P = in_sizes[1] / 2;
    const int C = in_sizes[0] / 256;
    const int nblocks = (P + 15) / 16;

    const size_t tab_bytes  = (size_t)C * 128;
    const size_t side_bytes = (size_t)C * 16;
    const size_t part_bytes = (size_t)nblocks * 2 * sizeof(float);
    const size_t need = tab_bytes + side_bytes + part_bytes;

    if (ws_size >= need) {
        char* base = (char*)d_ws;
        uint2*  tab  = (uint2*)base;
        float4* side = (float4*)(base + tab_bytes);
        float*  part = (float*)(base + tab_bytes + side_bytes);

        cvt_i4<<<(C + 15) / 16, 256, 0, stream>>>(proto, tab, side, C);
        cone_main_i4<<<nblocks, 256, 0, stream>>>(tab, side, pairs, negc, part, P);
        cone_final<<<1, 1024, 0, stream>>>(part, (float*)d_out, nblocks, P);
    } else {
        float* part = (float*)d_ws;
        cone_main_f32<<<nblocks, 256, 0, stream>>>(proto, pairs, negc, part, P);
        cone_final<<<1, 1024, 0, stream>>>(part, (float*)d_out, nblocks, P);
    }
}

// Round 10
// 165.137 us; speedup vs baseline: 1.7090x; 1.0436x over previous
//
#include <hip/hip_runtime.h>

#define BETA   0.1f
#define MARGIN 0.1f
#define EPSF   1e-6f
#define KNEG   4

__device__ __forceinline__ float gsum16(float v) {
    #pragma unroll
    for (int off = 8; off >= 1; off >>= 1) v += __shfl_xor(v, off, 64);
    return v;
}
__device__ __forceinline__ int gsum16i(int v) {
    #pragma unroll
    for (int off = 8; off >= 1; off >>= 1) v += __shfl_xor(v, off, 64);
    return v;
}
__device__ __forceinline__ float gmax16(float v) {
    #pragma unroll
    for (int off = 8; off >= 1; off >>= 1) v = fmaxf(v, __shfl_xor(v, off, 64));
    return v;
}
__device__ __forceinline__ float wave_sum(float v) {
    #pragma unroll
    for (int off = 32; off >= 1; off >>= 1) v += __shfl_xor(v, off, 64);
    return v;
}
__device__ __forceinline__ float dot4(float4 a, float4 b) {
    return a.x*b.x + a.y*b.y + a.z*b.z + a.w*b.w;
}

// ---- pass 1: SIGNED int4 table (128 B/row) + side {norm2, aperture, scale} ----
__global__ __launch_bounds__(256) void cvt_i4(
    const float* __restrict__ in, uint2* __restrict__ tab,
    float4* __restrict__ side, int C)
{
    const int sl  = threadIdx.x & 15;
    const int row = (blockIdx.x * 256 + threadIdx.x) >> 4;
    if (row >= C) return;
    const float4* src = (const float4*)(in + (size_t)row * 256);
    float4 v0 = src[4*sl+0], v1 = src[4*sl+1], v2 = src[4*sl+2], v3 = src[4*sl+3];
    float f[16] = { v0.x, v0.y, v0.z, v0.w,  v1.x, v1.y, v1.z, v1.w,
                    v2.x, v2.y, v2.z, v2.w,  v3.x, v3.y, v3.z, v3.w };
    float am = 0.f;
    #pragma unroll
    for (int d = 0; d < 16; ++d) am = fmaxf(am, fabsf(f[d]));
    am = gmax16(am);
    const float inv = (am > 0.f) ? (7.0f / am) : 0.f;
    unsigned u0 = 0, u1 = 0;
    #pragma unroll
    for (int n = 0; n < 8; ++n) {
        int c = (int)rintf(f[n] * inv);
        c = (c < -8) ? -8 : ((c > 7) ? 7 : c);
        u0 |= ((unsigned)c & 0xFu) << (4 * n);      // two's-complement nibble
    }
    #pragma unroll
    for (int n = 0; n < 8; ++n) {
        int c = (int)rintf(f[8 + n] * inv);
        c = (c < -8) ? -8 : ((c > 7) ? 7 : c);
        u1 |= ((unsigned)c & 0xFu) << (4 * n);
    }
    tab[(size_t)row * 16 + sl] = make_uint2(u0, u1);
    float ss = gsum16(dot4(v0,v0) + dot4(v1,v1) + dot4(v2,v2) + dot4(v3,v3));
    if (sl == 0) {
        float np = sqrtf(ss);
        float ap = asinf(fminf(fmaxf(BETA / (np + EPSF), 0.f), 1.f - EPSF));
        side[row] = make_float4(ss, ap, am * (1.f / 7.0f), 0.f);
    }
}

// Signed-nibble dot of 16 elems/lane: 2 x v_dot8_i32_i4 if available.
__device__ __forceinline__ int nib_dot(uint2 a, uint2 b) {
#if __has_builtin(__builtin_amdgcn_sdot8)
    int d = __builtin_amdgcn_sdot8((int)a.x, (int)b.x, 0, false);
    return  __builtin_amdgcn_sdot8((int)a.y, (int)b.y, d, false);
#else
    int acc = 0;
    #pragma unroll
    for (int n = 0; n < 8; ++n) {
        int pa = ((int)(a.x << (28 - 4*n))) >> 28;
        int pb = ((int)(b.x << (28 - 4*n))) >> 28;
        acc += pa * pb;
    }
    #pragma unroll
    for (int n = 0; n < 8; ++n) {
        int pa = ((int)(a.y << (28 - 4*n))) >> 28;
        int pb = ((int)(b.y << (28 - 4*n))) >> 28;
        acc += pa * pb;
    }
    return acc;
#endif
}

// ---- pass 2: gather + energy. sdot8 integer dots (exact); the wave's 20
// acos args are lane-parked and evaluated with ONE wave-wide acosf.
__global__ __launch_bounds__(256) void cone_main_i4(
    const uint2*  __restrict__ tab,
    const float4* __restrict__ side,
    const int*    __restrict__ pairs,
    const int*    __restrict__ negc,
    float*        __restrict__ part,
    int P)
{
    const int lane = threadIdx.x & 63;
    const int wid  = threadIdx.x >> 6;
    const int sub  = lane >> 4;
    const int sl   = lane & 15;
    const int pair = (blockIdx.x * 4 + wid) * 4 + sub;

    float pos_e = 0.f, neg_e = 0.f;
    if (pair < P) {
        const int pi = pairs[2 * pair];
        const int i0 = pairs[2 * pair + 1];
        const int i1 = negc[4 * pair + 0];
        const int i2 = negc[4 * pair + 1];
        const int i3 = negc[4 * pair + 2];
        const int i4 = negc[4 * pair + 3];

        // Issue ALL loads (6 rows + side) before compute.
        uint2 pu  = tab[(size_t)pi * 16 + sl];
        uint2 cu0 = tab[(size_t)i0 * 16 + sl];
        uint2 cu1 = tab[(size_t)i1 * 16 + sl];
        uint2 cu2 = tab[(size_t)i2 * 16 + sl];
        uint2 cu3 = tab[(size_t)i3 * 16 + sl];
        uint2 cu4 = tab[(size_t)i4 * 16 + sl];

        int tidx = pi;
        tidx = (sl == 1) ? i0 : tidx;
        tidx = (sl == 2) ? i1 : tidx;
        tidx = (sl == 3) ? i2 : tidx;
        tidx = (sl == 4) ? i3 : tidx;
        tidx = (sl == 5) ? i4 : tidx;
        float4 sd = side[tidx];

        const int base = sub * 16;
        const float p2 = __shfl(sd.x, base + 0, 64);
        const float ap = __shfl(sd.y, base + 0, 64);
        const float sp = __shfl(sd.z, base + 0, 64);
        const float np = sqrtf(p2);

        float my_ca = 1.f;   // park acos args; acos(1)=0 on idle lanes

#define CONE_STEP(J, CU)                                                      \
        {                                                                     \
            const float draw = (float)gsum16i(nib_dot(pu, CU));               \
            const float c2 = __shfl(sd.x, base + 1 + J, 64);                  \
            const float sc = __shfl(sd.z, base + 1 + J, 64);                  \
            const float dot = draw * sp * sc;                                 \
            const float num = 2.f * (dot - p2);                               \
            const float d2  = fmaxf(c2 + p2 - 2.f * dot, 0.f);                \
            const float den = 2.f * np * sqrtf(d2) + EPSF;                    \
            const float ca  = fminf(fmaxf(num / den, -1.f + EPSF), 1.f - EPSF);\
            my_ca = (sl == J) ? ca : my_ca;                                   \
        }
        CONE_STEP(0, cu0)
        CONE_STEP(1, cu1)
        CONE_STEP(2, cu2)
        CONE_STEP(3, cu3)
        CONE_STEP(4, cu4)
#undef CONE_STEP

        // ONE wave-wide acos covers all 20 parked values (4 pairs x 5).
        const float ang = acosf(my_ca);
        const float e   = fmaxf(ang - ap, 0.f);
        pos_e = (sl == 0) ? e : 0.f;
        const float neg_c = (sl >= 1 && sl <= 4) ? fmaxf(MARGIN - e, 0.f) : 0.f;
        neg_e = gsum16(neg_c);
    }

    __shared__ float spos[16], sneg[16];
    if (sl == 0) { spos[wid * 4 + sub] = pos_e; sneg[wid * 4 + sub] = neg_e; }
    __syncthreads();
    if (threadIdx.x == 0) {
        float ps = 0.f, ns = 0.f;
        #pragma unroll
        for (int i = 0; i < 16; ++i) { ps += spos[i]; ns += sneg[i]; }
        part[2 * blockIdx.x]     = ps;
        part[2 * blockIdx.x + 1] = ns;
    }
}

// ---- fp32 fallback (R2 kernel) if ws can't hold the tables ----
__global__ __launch_bounds__(256) void cone_main_f32(
    const float* __restrict__ proto,
    const int*   __restrict__ pairs,
    const int*   __restrict__ negc,
    float*       __restrict__ part,
    int P)
{
    const int lane = threadIdx.x & 63;
    const int wid  = threadIdx.x >> 6;
    const int sub  = lane >> 4;
    const int sl   = lane & 15;
    const int pair = (blockIdx.x * 4 + wid) * 4 + sub;

    float pos_e = 0.f, neg_e = 0.f;
    if (pair < P) {
        const int pi = pairs[2 * pair];
        const int i0 = pairs[2 * pair + 1];
        const int i1 = negc[4 * pair + 0];
        const int i2 = negc[4 * pair + 1];
        const int i3 = negc[4 * pair + 2];
        const int i4 = negc[4 * pair + 3];

        const float4* prow = (const float4*)(proto + (size_t)pi * 256);
        float4 pv[4];
        #pragma unroll
        for (int r = 0; r < 4; ++r) pv[r] = prow[sl + 16 * r];

        float pp = 0.f;
        #pragma unroll
        for (int r = 0; r < 4; ++r) pp += dot4(pv[r], pv[r]);
        float p2     = gsum16(pp);
        float norm_p = sqrtf(p2);
        float apert  = asinf(fminf(fmaxf(BETA / (norm_p + EPSF), 0.f), 1.f - EPSF));

#define CONE_F32_STEP(J, IDX)                                                 \
        {                                                                     \
            const float4* crow = (const float4*)(proto + (size_t)(IDX) * 256);\
            float cc = 0.f, dd = 0.f;                                         \
            _Pragma("unroll")                                                 \
            for (int r = 0; r < 4; ++r) {                                     \
                float4 c = crow[sl + 16 * r], p = pv[r];                      \
                cc += dot4(c, c);                                             \
                float dx = c.x-p.x, dy = c.y-p.y, dz = c.z-p.z, dw = c.w-p.w; \
                dd += dx*dx + dy*dy + dz*dz + dw*dw;                          \
            }                                                                 \
            float c2 = gsum16(cc);                                            \
            float d2 = gsum16(dd);                                            \
            float num    = c2 - p2 - d2;                                      \
            float den    = 2.f * norm_p * sqrtf(d2) + EPSF;                   \
            float cosang = fminf(fmaxf(num / den, -1.f + EPSF), 1.f - EPSF);  \
            float e      = fmaxf(acosf(cosang) - apert, 0.f);                 \
            if (J == 0) pos_e = e;                                            \
            else        neg_e += fmaxf(MARGIN - e, 0.f);                      \
        }
        CONE_F32_STEP(0, i0)
        CONE_F32_STEP(1, i1)
        CONE_F32_STEP(2, i2)
        CONE_F32_STEP(3, i3)
        CONE_F32_STEP(4, i4)
#undef CONE_F32_STEP
    }

    __shared__ float sp[16], sn[16];
    if (sl == 0) { sp[wid * 4 + sub] = pos_e; sn[wid * 4 + sub] = neg_e; }
    __syncthreads();
    if (threadIdx.x == 0) {
        float ps = 0.f, ns = 0.f;
        #pragma unroll
        for (int i = 0; i < 16; ++i) { ps += sp[i]; ns += sn[i]; }
        part[2 * blockIdx.x]     = ps;
        part[2 * blockIdx.x + 1] = ns;
    }
}

__global__ __launch_bounds__(1024) void cone_final(
    const float* __restrict__ part, float* __restrict__ out, int nblocks, int P)
{
    float ps = 0.f, ns = 0.f;
    for (int i = threadIdx.x; i < nblocks; i += 1024) {
        ps += part[2 * i];
        ns += part[2 * i + 1];
    }
    ps = wave_sum(ps);
    ns = wave_sum(ns);
    const int lane = threadIdx.x & 63, wid = threadIdx.x >> 6;
    __shared__ float sp[16], sn[16];
    if (lane == 0) { sp[wid] = ps; sn[wid] = ns; }
    __syncthreads();
    if (threadIdx.x == 0) {
        float tp = 0.f, tn = 0.f;
        #pragma unroll
        for (int i = 0; i < 16; ++i) { tp += sp[i]; tn += sn[i]; }
        float fP = (float)P;
        out[0] = (tp / fP + tn / (fP * (float)KNEG)) * 0.5f;
    }
}

extern "C" void kernel_launch(void* const* d_in, const int* in_sizes, int n_in,
                              void* d_out, int out_size, void* d_ws, size_t ws_size,
                              hipStream_t stream) {
    const float* proto = (const float*)d_in[0];
    const int*   pairs = (const int*)d_in[1];
    const int*   negc  = (const int*)d_in[2];
    const int P = in_sizes[1] / 2;
    const int C = in_sizes[0] / 256;
    const int nblocks = (P + 15) / 16;

    const size_t tab_bytes  = (size_t)C * 128;
    const size_t side_bytes = (size_t)C * 16;
    const size_t part_bytes = (size_t)nblocks * 2 * sizeof(float);
    const size_t need = tab_bytes + side_bytes + part_bytes;

    if (ws_size >= need) {
        char* base = (char*)d_ws;
        uint2*  tab  = (uint2*)base;
        float4* side = (float4*)(base + tab_bytes);
        float*  part = (float*)(base + tab_bytes + side_bytes);

        cvt_i4<<<(C + 15) / 16, 256, 0, stream>>>(proto, tab, side, C);
        cone_main_i4<<<nblocks, 256, 0, stream>>>(tab, side, pairs, negc, part, P);
        cone_final<<<1, 1024, 0, stream>>>(part, (float*)d_out, nblocks, P);
    } else {
        float* part = (float*)d_ws;
        cone_main_f32<<<nblocks, 256, 0, stream>>>(proto, pairs, negc, part, P);
        cone_final<<<1, 1024, 0, stream>>>(part, (float*)d_out, nblocks, P);
    }
}